// Round 8
// baseline (168.651 us; speedup 1.0000x reference)
//
#include <hip/hip_runtime.h>

#define C 128
#define CHUNK 2048     // edges per K1/K3 block
#define K4CAP 6144     // LDS record capacity per bucket (avg 4082, sigma ~64)

typedef short bf16x8 __attribute__((ext_vector_type(8)));
typedef float f32x4 __attribute__((ext_vector_type(4)));

__device__ inline unsigned short f2bf(float f) {   // RNE f32 -> bf16
    unsigned u = __float_as_uint(f);
    u += 0x7fffu + ((u >> 16) & 1u);
    return (unsigned short)(u >> 16);
}

__device__ inline unsigned pk2bf(float lo, float hi) {
    return (unsigned)f2bf(lo) | ((unsigned)f2bf(hi) << 16);
}

// ---- GEMM role: xts(bf16) = x @ W (UNscaled; dis applied in gather) --------
// One 256-thread block computes 64 rows x 128 cols via mfma_f32_16x16x32_bf16.
__device__ inline void gemm_rows(const float* __restrict__ x,
                                 const unsigned short* __restrict__ Wt,
                                 unsigned short* __restrict__ xts, int n, int blk) {
    const int t = threadIdx.x;
    const int lane = t & 63;
    const int wave = t >> 6;
    const int m = lane & 15;
    const int q = lane >> 4;
    const int r0 = blk * 64 + wave * 16;
    const int row = r0 + m;
    const int rowc = (row < n) ? row : (n - 1);

    f32x4 acc[8];
#pragma unroll
    for (int nt = 0; nt < 8; ++nt) acc[nt] = (f32x4){0.f, 0.f, 0.f, 0.f};

#pragma unroll
    for (int kb = 0; kb < 4; ++kb) {
        const int k0 = kb * 32 + q * 8;
        const float4* xp = (const float4*)(x + (size_t)rowc * 128 + k0);
        float4 xa = xp[0];
        float4 xb = xp[1];
        union { unsigned u[4]; bf16x8 v; } af;
        af.u[0] = pk2bf(xa.x, xa.y);
        af.u[1] = pk2bf(xa.z, xa.w);
        af.u[2] = pk2bf(xb.x, xb.y);
        af.u[3] = pk2bf(xb.z, xb.w);
#pragma unroll
        for (int nt = 0; nt < 8; ++nt) {
            bf16x8 bf = *(const bf16x8*)(Wt + (size_t)(nt * 16 + m) * 128 + k0);
            acc[nt] = __builtin_amdgcn_mfma_f32_16x16x32_bf16(af.v, bf, acc[nt], 0, 0, 0);
        }
    }
#pragma unroll
    for (int nt = 0; nt < 8; ++nt) {
        int col = nt * 16 + m;
#pragma unroll
        for (int r = 0; r < 4; ++r) {
            int gr = r0 + q * 4 + r;
            if (gr < n) xts[(size_t)gr * 128 + col] = f2bf(acc[nt][r]);
        }
    }
}

// K1: per-chunk LDS histogram of dst>>8 -> H[bucket][block]; wcvt fused.
__global__ __launch_bounds__(256) void k1_hist(
        const int* __restrict__ ei, int e, int* __restrict__ H,
        int nblocks, int nbuck,
        const float* __restrict__ W, unsigned short* __restrict__ Wt) {
    int b = blockIdx.x;
    int t = threadIdx.x;
    if (b >= nblocks) {   // wcvt: 64 blocks x 256 -> Wt[n][k] = bf16(W[k][n])
        int i = (b - nblocks) * 256 + t;
        int nn = i >> 7, k = i & 127;
        Wt[nn * 128 + k] = f2bf(W[k * 128 + nn]);
        return;
    }
    __shared__ int h[256];
    h[t] = 0;
    __syncthreads();
    int base = b * CHUNK;
    int lim = min(CHUNK, e - base);
    for (int i = t; i < lim; i += 256)
        atomicAdd(&h[ei[e + base + i] >> 8], 1);
    __syncthreads();
    if (t < nbuck) H[t * nblocks + b] = h[t];
}

// K2a (+ gemm slice): block g < nbuck scans its bucket row H[g][0..nblocks)
// (looped, nblocks may exceed 256) -> bucket-local exclusive offsets; total->tot.
__global__ __launch_bounds__(256) void k2a_gemm(
        int* __restrict__ H, int* __restrict__ tot, int nblocks, int nbuck,
        const float* __restrict__ x, const unsigned short* __restrict__ Wt,
        unsigned short* __restrict__ xts, int n, int g0) {
    __shared__ int s[256];
    int t = threadIdx.x;
    if ((int)blockIdx.x >= nbuck) {
        gemm_rows(x, Wt, xts, n, g0 + (int)blockIdx.x - nbuck);
        return;
    }
    int g = blockIdx.x;
    int carry = 0;
    for (int base = 0; base < nblocks; base += 256) {
        int v = (base + t < nblocks) ? H[g * nblocks + base + t] : 0;
        s[t] = v;
        __syncthreads();
        for (int off = 1; off < 256; off <<= 1) {
            int u = (t >= off) ? s[t - off] : 0;
            __syncthreads();
            s[t] += u;
            __syncthreads();
        }
        if (base + t < nblocks) H[g * nblocks + base + t] = carry + s[t] - v;
        int bs = s[255];
        __syncthreads();
        carry += bs;
    }
    if (t == 0) tot[g] = carry;
}

// K2b (+ gemm slice): block 0 scans bucket totals -> bbase; bbase[nbuck]=e.
__global__ __launch_bounds__(256) void k2b_gemm(
        const int* __restrict__ tot, int* __restrict__ bbase, int nbuck, int e,
        const float* __restrict__ x, const unsigned short* __restrict__ Wt,
        unsigned short* __restrict__ xts, int n, int g0) {
    __shared__ int s[256];
    int t = threadIdx.x;
    if (blockIdx.x > 0) {
        gemm_rows(x, Wt, xts, n, g0 + (int)blockIdx.x - 1);
        return;
    }
    int v = (t < nbuck) ? tot[t] : 0;
    s[t] = v;
    __syncthreads();
    for (int off = 1; off < 256; off <<= 1) {
        int u = (t >= off) ? s[t - off] : 0;
        __syncthreads();
        s[t] += u;
        __syncthreads();
    }
    if (t < nbuck) bbase[t] = s[t] - v;
    if (t == 0) bbase[nbuck] = e;
}

// K3 (+ gemm slice): rank edges via LDS cursors, write 4B records
// (dstlow:8)<<16 | src to per-block-disjoint contiguous runs.
__global__ __launch_bounds__(256) void k3_gemm(
        const int* __restrict__ ei, int e, const int* __restrict__ H,
        const int* __restrict__ bbase, unsigned* __restrict__ staging,
        int nblocks, int nbuck,
        const float* __restrict__ x, const unsigned short* __restrict__ Wt,
        unsigned short* __restrict__ xts, int n, int g0) {
    __shared__ int cur[256];
    int t = threadIdx.x;
    if ((int)blockIdx.x >= nblocks) {
        gemm_rows(x, Wt, xts, n, g0 + (int)blockIdx.x - nblocks);
        return;
    }
    int b = blockIdx.x;
    if (t < nbuck) cur[t] = bbase[t] + H[t * nblocks + b];
    __syncthreads();
    int base = b * CHUNK;
    int lim = min(CHUNK, e - base);
    for (int i = t; i < lim; i += 256) {
        int src = ei[base + i];
        int dst = ei[e + base + i];
        int pos = atomicAdd(&cur[dst >> 8], 1);
        staging[pos] = (unsigned)src | ((unsigned)(dst & 255) << 16);
    }
}

// K4: one block per bucket, single global pass. Records staged in LDS during
// the histogram pass; scan -> row_ptr/dis; LDS-sourced scatter -> srcs(ushort).
__global__ __launch_bounds__(256) void k4_finalize(
        const unsigned* __restrict__ staging, const int* __restrict__ bbase,
        int* __restrict__ row_ptr, float* __restrict__ dis,
        unsigned short* __restrict__ srcs, int n) {
    __shared__ unsigned rec[K4CAP];
    __shared__ int sc[256];
    __shared__ int cur[256];
    int g = blockIdx.x, t = threadIdx.x;
    int s0 = bbase[g], s1 = bbase[g + 1];
    int cnt = s1 - s0;
    sc[t] = 0;
    __syncthreads();
    for (int li = t; li < cnt; li += 256) {
        unsigned r = staging[s0 + li];
        if (li < K4CAP) rec[li] = r;
        atomicAdd(&sc[r >> 16], 1);
    }
    __syncthreads();
    int v = sc[t];
    __syncthreads();
    for (int off = 1; off < 256; off <<= 1) {
        int u = (t >= off) ? sc[t - off] : 0;
        __syncthreads();
        sc[t] += u;
        __syncthreads();
    }
    int excl = sc[t] - v;
    int idx = g * 256 + t;
    if (idx <= n) row_ptr[idx] = s0 + excl;
    if (idx < n) dis[idx] = rsqrtf((float)(v + 1));
    cur[t] = s0 + excl;
    __syncthreads();
    for (int li = t; li < cnt; li += 256) {
        unsigned r = (li < K4CAP) ? rec[li] : staging[s0 + li];
        int pos = atomicAdd(&cur[r >> 16], 1);
        srcs[pos] = (unsigned short)(r & 0xffffu);
    }
}

__device__ inline void fma8(float* a, uint4 w, float s) {
    a[0] = fmaf(__uint_as_float(w.x << 16), s, a[0]);
    a[1] = fmaf(__uint_as_float(w.x & 0xffff0000u), s, a[1]);
    a[2] = fmaf(__uint_as_float(w.y << 16), s, a[2]);
    a[3] = fmaf(__uint_as_float(w.y & 0xffff0000u), s, a[3]);
    a[4] = fmaf(__uint_as_float(w.z << 16), s, a[4]);
    a[5] = fmaf(__uint_as_float(w.z & 0xffff0000u), s, a[5]);
    a[6] = fmaf(__uint_as_float(w.w << 16), s, a[6]);
    a[7] = fmaf(__uint_as_float(w.w & 0xffff0000u), s, a[7]);
}

// out[i] = dis[i]*(xts[i]*dis[i] + sum_in xts[src]*dis[src]) + bias
// 16 lanes/node, 16B/lane bf16, x4 unroll, dual accumulators.
__global__ void gather4(const int* __restrict__ row_ptr,
                        const unsigned short* __restrict__ srcs,
                        const unsigned short* __restrict__ xts,
                        const float* __restrict__ dis,
                        const float* __restrict__ bias, float* __restrict__ out, int n) {
    int node = blockIdx.x * 16 + (threadIdx.x >> 4);
    int q = threadIdx.x & 15;
    if (node >= n) return;
    const uint4* x4 = (const uint4*)xts;
    float d = dis[node];
    int start = row_ptr[node];
    int end = row_ptr[node + 1];
    float a0[8] = {0, 0, 0, 0, 0, 0, 0, 0};
    float a1[8] = {0, 0, 0, 0, 0, 0, 0, 0};
    fma8(a0, x4[node * 16 + q], d);        // self-loop
    int j = start;
    for (; j + 4 <= end; j += 4) {
        int s0 = srcs[j], s1 = srcs[j + 1], s2 = srcs[j + 2], s3 = srcs[j + 3];
        float w0 = dis[s0], w1 = dis[s1], w2 = dis[s2], w3 = dis[s3];
        uint4 m0 = x4[s0 * 16 + q];
        uint4 m1 = x4[s1 * 16 + q];
        uint4 m2 = x4[s2 * 16 + q];
        uint4 m3 = x4[s3 * 16 + q];
        fma8(a0, m0, w0);
        fma8(a1, m1, w1);
        fma8(a0, m2, w2);
        fma8(a1, m3, w3);
    }
    for (; j < end; ++j) {
        int s = srcs[j];
        fma8(a0, x4[s * 16 + q], dis[s]);
    }
    const float4 b0 = ((const float4*)bias)[q * 2];
    const float4 b1 = ((const float4*)bias)[q * 2 + 1];
    float4 o0, o1;
    o0.x = (a0[0] + a1[0]) * d + b0.x;
    o0.y = (a0[1] + a1[1]) * d + b0.y;
    o0.z = (a0[2] + a1[2]) * d + b0.z;
    o0.w = (a0[3] + a1[3]) * d + b0.w;
    o1.x = (a0[4] + a1[4]) * d + b1.x;
    o1.y = (a0[5] + a1[5]) * d + b1.y;
    o1.z = (a0[6] + a1[6]) * d + b1.z;
    o1.w = (a0[7] + a1[7]) * d + b1.w;
    float4* op = (float4*)(out + node * 128 + q * 8);
    op[0] = o0;
    op[1] = o1;
}

extern "C" void kernel_launch(void* const* d_in, const int* in_sizes, int n_in,
                              void* d_out, int out_size, void* d_ws, size_t ws_size,
                              hipStream_t stream) {
    const float* x    = (const float*)d_in[0];
    const int*   ei   = (const int*)d_in[1];
    const float* W    = (const float*)d_in[2];
    const float* bias = (const float*)d_in[3];
    float* out = (float*)d_out;

    const int n = in_sizes[0] / C;               // 50000 (< 65536)
    const int e = in_sizes[1] / 2;               // 800000
    const int nblocks = (e + CHUNK - 1) / CHUNK; // 391
    const int nbuck = (n + 255) >> 8;            // 196 (<=256)

    const int G = (n + 63) / 64;                 // gemm blocks total (782)
    const int gA = G / 3;                        // slice sizes
    const int gB = G / 3;
    const int gC = G - gA - gB;

    char* p = (char*)d_ws;
    auto alloc = [&](size_t bytes) {
        char* r = p;
        p += (bytes + 15) & ~(size_t)15;
        return (void*)r;
    };
    int*      H       = (int*)alloc((size_t)nbuck * nblocks * 4);
    int*      tot     = (int*)alloc(nbuck * 4);
    int*      bbase   = (int*)alloc((nbuck + 1) * 4);
    unsigned* staging = (unsigned*)alloc((size_t)e * 4);
    int*      row_ptr = (int*)alloc((n + 1) * 4);
    float*    dis     = (float*)alloc(n * 4);
    unsigned short* srcs = (unsigned short*)alloc((size_t)e * 2);
    unsigned short* xts  = (unsigned short*)alloc((size_t)n * C * 2);
    unsigned short* Wt   = (unsigned short*)alloc(128 * 128 * 2);

    k1_hist<<<nblocks + 64, 256, 0, stream>>>(ei, e, H, nblocks, nbuck, W, Wt);
    k2a_gemm<<<nbuck + gA, 256, 0, stream>>>(H, tot, nblocks, nbuck,
                                             x, Wt, xts, n, 0);
    k2b_gemm<<<1 + gB, 256, 0, stream>>>(tot, bbase, nbuck, e,
                                         x, Wt, xts, n, gA);
    k3_gemm<<<nblocks + gC, 256, 0, stream>>>(ei, e, H, bbase, staging,
                                              nblocks, nbuck,
                                              x, Wt, xts, n, gA + gB);
    k4_finalize<<<nbuck, 256, 0, stream>>>(staging, bbase, row_ptr, dis, srcs, n);
    gather4<<<(n + 15) / 16, 256, 0, stream>>>(row_ptr, srcs, xts, dis, bias, out, n);
}